// Round 1
// baseline (1314.426 us; speedup 1.0000x reference)
//
#include <hip/hip_runtime.h>
#include <math.h>

// Problem constants (fixed-shape problem): B=4096 rows each in x,y; D=3072; N=50000.
#define BSZ 4096
#define DDIM 3072
#define BM 128
#define BN 128
#define BKK 16
#define TM 8
#define TN 8

// Monotonic float->uint mapping so unsigned compare == float compare.
__device__ __forceinline__ unsigned long long pack_key(float t, unsigned int j) {
    unsigned int b = __float_as_uint(t);
    b = (b & 0x80000000u) ? ~b : (b | 0x80000000u);
    return ((unsigned long long)b << 32) | (unsigned long long)j;
}

__device__ __forceinline__ float unpack_val(unsigned long long key) {
    unsigned int ub = (unsigned int)(key >> 32);
    unsigned int b = (ub & 0x80000000u) ? (ub ^ 0x80000000u) : ~ub;
    return __uint_as_float(b);
}

// Compute squared row norms of x and y; init keys to +inf.
__global__ __launch_bounds__(256)
void norms_init_kernel(const float* __restrict__ x, const float* __restrict__ y,
                       float* __restrict__ x2, float* __restrict__ y2,
                       unsigned long long* __restrict__ keys) {
    const int row = blockIdx.x;              // 0..2*BSZ-1
    const float* p = (row < BSZ) ? (x + (size_t)row * DDIM)
                                 : (y + (size_t)(row - BSZ) * DDIM);
    const float4* p4 = (const float4*)p;
    const int D4 = DDIM / 4;                 // 768
    float s = 0.f;
    for (int k = threadIdx.x; k < D4; k += 256) {
        float4 v = p4[k];
        s += v.x * v.x + v.y * v.y + v.z * v.z + v.w * v.w;
    }
    #pragma unroll
    for (int off = 32; off > 0; off >>= 1) s += __shfl_down(s, off, 64);
    __shared__ float ls[4];
    const int lane = threadIdx.x & 63, w = threadIdx.x >> 6;
    if (lane == 0) ls[w] = s;
    __syncthreads();
    if (threadIdx.x == 0) {
        float tot = ls[0] + ls[1] + ls[2] + ls[3];
        if (row < BSZ) { x2[row] = tot; keys[row] = ~0ull; }
        else           { y2[row - BSZ] = tot; }
    }
}

// 128x128x16 fp32 tile GEMM computing t = y2[j] - 2*dot(x_i, y_j),
// reduced to per-row min(+argmin) via packed u64 atomicMin.
__global__ __launch_bounds__(256)
void gemm_min_kernel(const float* __restrict__ x, const float* __restrict__ y,
                     const float* __restrict__ y2,
                     unsigned long long* __restrict__ keys) {
    __shared__ float As[BKK][BM + 4];
    __shared__ float Bs[BKK][BN + 4];
    __shared__ unsigned long long rowmin[BM];

    const int tid  = threadIdx.x;
    const int row0 = blockIdx.y * BM;
    const int col0 = blockIdx.x * BN;
    const int tx   = tid & 15;
    const int ty   = tid >> 4;

    float acc[TM][TN];
    #pragma unroll
    for (int m = 0; m < TM; m++)
        #pragma unroll
        for (int n = 0; n < TN; n++) acc[m][n] = 0.f;

    // Staging: 256 threads load 128x16 of A and B as float4 along K, store transposed.
    const int lrow = tid >> 2;          // 0..63
    const int lcol = (tid & 3) << 2;    // 0,4,8,12

    const float* Abase = x + (size_t)row0 * DDIM;
    const float* Bbase = y + (size_t)col0 * DDIM;

    for (int k0 = 0; k0 < DDIM; k0 += BKK) {
        #pragma unroll
        for (int r = 0; r < 2; r++) {
            const int rr = lrow + r * 64;
            float4 va = *(const float4*)(Abase + (size_t)rr * DDIM + k0 + lcol);
            float4 vb = *(const float4*)(Bbase + (size_t)rr * DDIM + k0 + lcol);
            As[lcol + 0][rr] = va.x; As[lcol + 1][rr] = va.y;
            As[lcol + 2][rr] = va.z; As[lcol + 3][rr] = va.w;
            Bs[lcol + 0][rr] = vb.x; Bs[lcol + 1][rr] = vb.y;
            Bs[lcol + 2][rr] = vb.z; Bs[lcol + 3][rr] = vb.w;
        }
        __syncthreads();
        #pragma unroll
        for (int k = 0; k < BKK; k++) {
            float4 a0 = *(const float4*)&As[k][ty * TM];
            float4 a1 = *(const float4*)&As[k][ty * TM + 4];
            float4 b0 = *(const float4*)&Bs[k][tx * TN];
            float4 b1 = *(const float4*)&Bs[k][tx * TN + 4];
            float a[TM] = {a0.x, a0.y, a0.z, a0.w, a1.x, a1.y, a1.z, a1.w};
            float b[TN] = {b0.x, b0.y, b0.z, b0.w, b1.x, b1.y, b1.z, b1.w};
            #pragma unroll
            for (int m = 0; m < TM; m++)
                #pragma unroll
                for (int n = 0; n < TN; n++)
                    acc[m][n] = fmaf(a[m], b[n], acc[m][n]);
        }
        __syncthreads();
    }

    if (tid < BM) rowmin[tid] = ~0ull;
    __syncthreads();

    #pragma unroll
    for (int m = 0; m < TM; m++) {
        const int i = ty * TM + m;
        unsigned long long best = ~0ull;
        #pragma unroll
        for (int n = 0; n < TN; n++) {
            const int j = col0 + tx * TN + n;
            const float t = y2[j] - 2.0f * acc[m][n];
            const unsigned long long key = pack_key(t, (unsigned int)j);
            best = (key < best) ? key : best;
        }
        atomicMin(&rowmin[i], best);
    }
    __syncthreads();
    if (tid < BM) atomicMin(&keys[row0 + tid], rowmin[tid]);
}

// Write both outputs: copy-through everywhere, fused update on [xs, xs+BSZ).
__global__ __launch_bounds__(256)
void finalize_kernel(const float* __restrict__ mind_in, const int* __restrict__ nn_in,
                     const int* __restrict__ xs_p, const int* __restrict__ ys_p,
                     const unsigned long long* __restrict__ keys,
                     const float* __restrict__ x2,
                     float* __restrict__ out_mind, float* __restrict__ out_nn, int N) {
    const int n = blockIdx.x * blockDim.x + threadIdx.x;
    if (n >= N) return;
    const int xs = *xs_p, ys = *ys_p;
    float md  = mind_in[n];
    float nnv = (float)nn_in[n];
    const int i = n - xs;
    if (i >= 0 && i < BSZ) {
        const unsigned long long key = keys[i];
        const float t  = unpack_val(key);
        const float d2 = x2[i] + t;
        const float d  = sqrtf(fmaxf(d2, 0.f));
        md  = fminf(md, d);                                   // min with old buffer
        nnv = (float)((int)(key & 0xFFFFFFFFull) + ys);       // unconditional overwrite
    }
    out_mind[n] = md;
    out_nn[n]  = nnv;
}

extern "C" void kernel_launch(void* const* d_in, const int* in_sizes, int n_in,
                              void* d_out, int out_size, void* d_ws, size_t ws_size,
                              hipStream_t stream) {
    const float* x       = (const float*)d_in[0];
    const float* y       = (const float*)d_in[1];
    const float* mind_in = (const float*)d_in[2];
    const int*   nn_in   = (const int*)d_in[3];
    const int*   xs_p    = (const int*)d_in[4];
    const int*   ys_p    = (const int*)d_in[5];
    const int N = in_sizes[2];            // 50000

    // Workspace layout: [keys u64 x 4096][x2 f32 x 4096][y2 f32 x 4096] = 64 KB
    unsigned long long* keys = (unsigned long long*)d_ws;
    float* x2 = (float*)((char*)d_ws + BSZ * sizeof(unsigned long long));
    float* y2 = x2 + BSZ;

    float* out_mind = (float*)d_out;
    float* out_nn   = out_mind + N;

    norms_init_kernel<<<2 * BSZ, 256, 0, stream>>>(x, y, x2, y2, keys);

    dim3 grid(BSZ / BN, BSZ / BM);        // 32 x 32 = 1024 blocks
    gemm_min_kernel<<<grid, 256, 0, stream>>>(x, y, y2, keys);

    finalize_kernel<<<(N + 255) / 256, 256, 0, stream>>>(
        mind_in, nn_in, xs_p, ys_p, keys, x2, out_mind, out_nn, N);
}

// Round 2
// 478.434 us; speedup vs baseline: 2.7474x; 2.7474x over previous
//
#include <hip/hip_runtime.h>
#include <math.h>

// Problem constants (fixed-shape): B=4096 rows each in x,y; D=3072; N=50000.
#define BSZ 4096
#define DDIM 3072
#define BM 128
#define BN 128
#define BK 32
#define LDK 40   // padded LDS row length in f16 (32 + 8) -> 2-way bank pattern (free)

typedef _Float16 half8 __attribute__((ext_vector_type(8)));
typedef float    floatx4 __attribute__((ext_vector_type(4)));

// Monotonic float->uint mapping so unsigned compare == float compare.
__device__ __forceinline__ unsigned long long pack_key(float t, unsigned int j) {
    unsigned int b = __float_as_uint(t);
    b = (b & 0x80000000u) ? ~b : (b | 0x80000000u);
    return ((unsigned long long)b << 32) | (unsigned long long)j;
}

__device__ __forceinline__ float unpack_val(unsigned long long key) {
    unsigned int ub = (unsigned int)(key >> 32);
    unsigned int b = (ub & 0x80000000u) ? (ub ^ 0x80000000u) : ~ub;
    return __uint_as_float(b);
}

// Compute squared row norms of x and y; init keys to +inf.
__global__ __launch_bounds__(256)
void norms_init_kernel(const float* __restrict__ x, const float* __restrict__ y,
                       float* __restrict__ x2, float* __restrict__ y2,
                       unsigned long long* __restrict__ keys) {
    const int row = blockIdx.x;              // 0..2*BSZ-1
    const float* p = (row < BSZ) ? (x + (size_t)row * DDIM)
                                 : (y + (size_t)(row - BSZ) * DDIM);
    const float4* p4 = (const float4*)p;
    const int D4 = DDIM / 4;                 // 768
    float s = 0.f;
    for (int k = threadIdx.x; k < D4; k += 256) {
        float4 v = p4[k];
        s += v.x * v.x + v.y * v.y + v.z * v.z + v.w * v.w;
    }
    #pragma unroll
    for (int off = 32; off > 0; off >>= 1) s += __shfl_down(s, off, 64);
    __shared__ float ls[4];
    const int lane = threadIdx.x & 63, w = threadIdx.x >> 6;
    if (lane == 0) ls[w] = s;
    __syncthreads();
    if (threadIdx.x == 0) {
        float tot = ls[0] + ls[1] + ls[2] + ls[3];
        if (row < BSZ) { x2[row] = tot; keys[row] = ~0ull; }
        else           { y2[row - BSZ] = tot; }
    }
}

// Split a float into hi/lo f16 pair: hi = f16(v), lo = f16(v - hi).
__device__ __forceinline__ void split_f16(float v, _Float16& hi, _Float16& lo) {
    hi = (_Float16)v;
    lo = (_Float16)(v - (float)hi);
}

// 128x128 tile GEMM on matrix cores via split-f16 (3-product) emulation.
// Computes t = y2[j] - 2*dot(x_i,y_j); per-row min/argmin via packed u64 atomicMin.
__global__ __launch_bounds__(256, 3)
void gemm_min_kernel(const float* __restrict__ x, const float* __restrict__ y,
                     const float* __restrict__ y2,
                     unsigned long long* __restrict__ keys) {
    __shared__ _Float16 Ahi[BM * LDK];
    __shared__ _Float16 Alo[BM * LDK];
    __shared__ _Float16 Bhi[BN * LDK];
    __shared__ _Float16 Blo[BN * LDK];
    __shared__ unsigned long long rowmin[BM];

    const int tid  = threadIdx.x;
    const int row0 = blockIdx.y * BM;
    const int col0 = blockIdx.x * BN;

    const int wid    = tid >> 6;       // 0..3
    const int lane   = tid & 63;
    const int wave_m = wid & 1;        // 0..1  (64-row half)
    const int wave_n = wid >> 1;       // 0..1  (64-col half)
    const int lrow   = lane & 15;
    const int quad   = lane >> 4;

    floatx4 acc[4][4];
    #pragma unroll
    for (int m = 0; m < 4; m++)
        #pragma unroll
        for (int n = 0; n < 4; n++) acc[m][n] = (floatx4){0.f, 0.f, 0.f, 0.f};

    if (tid < BM) rowmin[tid] = ~0ull;

    // Staging mapping: thread t handles row r = t>>1 (0..127), half h = t&1
    // (16 floats each), for both A (x) and B (y).
    const int sr = tid >> 1;
    const int sh = tid & 1;
    const float* Asrc = x + (size_t)(row0 + sr) * DDIM + sh * 16;
    const float* Bsrc = y + (size_t)(col0 + sr) * DDIM + sh * 16;
    _Float16* AhiW = &Ahi[sr * LDK + sh * 16];
    _Float16* AloW = &Alo[sr * LDK + sh * 16];
    _Float16* BhiW = &Bhi[sr * LDK + sh * 16];
    _Float16* BloW = &Blo[sr * LDK + sh * 16];

    for (int k0 = 0; k0 < DDIM; k0 += BK) {
        // ---- stage A and B tiles: fp32 global -> split f16 hi/lo -> LDS ----
        {
            float4 a0 = *(const float4*)(Asrc + k0 + 0);
            float4 a1 = *(const float4*)(Asrc + k0 + 4);
            float4 a2 = *(const float4*)(Asrc + k0 + 8);
            float4 a3 = *(const float4*)(Asrc + k0 + 12);
            float4 b0 = *(const float4*)(Bsrc + k0 + 0);
            float4 b1 = *(const float4*)(Bsrc + k0 + 4);
            float4 b2 = *(const float4*)(Bsrc + k0 + 8);
            float4 b3 = *(const float4*)(Bsrc + k0 + 12);
            float av[16] = {a0.x,a0.y,a0.z,a0.w, a1.x,a1.y,a1.z,a1.w,
                            a2.x,a2.y,a2.z,a2.w, a3.x,a3.y,a3.z,a3.w};
            float bv[16] = {b0.x,b0.y,b0.z,b0.w, b1.x,b1.y,b1.z,b1.w,
                            b2.x,b2.y,b2.z,b2.w, b3.x,b3.y,b3.z,b3.w};
            half8 ah0, ah1, al0, al1, bh0, bh1, bl0, bl1;
            #pragma unroll
            for (int i = 0; i < 8; i++) {
                _Float16 hi, lo;
                split_f16(av[i], hi, lo);     ah0[i] = hi; al0[i] = lo;
                split_f16(av[i + 8], hi, lo); ah1[i] = hi; al1[i] = lo;
                split_f16(bv[i], hi, lo);     bh0[i] = hi; bl0[i] = lo;
                split_f16(bv[i + 8], hi, lo); bh1[i] = hi; bl1[i] = lo;
            }
            __syncthreads();   // protect LDS from previous iteration's readers
            *(half8*)(AhiW + 0) = ah0;  *(half8*)(AhiW + 8) = ah1;
            *(half8*)(AloW + 0) = al0;  *(half8*)(AloW + 8) = al1;
            *(half8*)(BhiW + 0) = bh0;  *(half8*)(BhiW + 8) = bh1;
            *(half8*)(BloW + 0) = bl0;  *(half8*)(BloW + 8) = bl1;
        }
        __syncthreads();

        // ---- fragments + MFMA ----
        half8 fah[4], fal[4], fbh[4], fbl[4];
        #pragma unroll
        for (int m = 0; m < 4; m++) {
            const int r = wave_m * 64 + m * 16 + lrow;
            fah[m] = *(const half8*)&Ahi[r * LDK + quad * 8];
            fal[m] = *(const half8*)&Alo[r * LDK + quad * 8];
        }
        #pragma unroll
        for (int n = 0; n < 4; n++) {
            const int c = wave_n * 64 + n * 16 + lrow;
            fbh[n] = *(const half8*)&Bhi[c * LDK + quad * 8];
            fbl[n] = *(const half8*)&Blo[c * LDK + quad * 8];
        }
        #pragma unroll
        for (int m = 0; m < 4; m++)
            #pragma unroll
            for (int n = 0; n < 4; n++) {
                acc[m][n] = __builtin_amdgcn_mfma_f32_16x16x32_f16(fah[m], fbh[n], acc[m][n], 0, 0, 0);
                acc[m][n] = __builtin_amdgcn_mfma_f32_16x16x32_f16(fah[m], fbl[n], acc[m][n], 0, 0, 0);
                acc[m][n] = __builtin_amdgcn_mfma_f32_16x16x32_f16(fal[m], fbh[n], acc[m][n], 0, 0, 0);
            }
    }
    __syncthreads();

    // ---- epilogue: per-row min/argmin over this block's 128 columns ----
    float y2v[4];
    int   jv[4];
    #pragma unroll
    for (int n = 0; n < 4; n++) {
        jv[n]  = col0 + wave_n * 64 + n * 16 + lrow;
        y2v[n] = y2[jv[n]];
    }
    #pragma unroll
    for (int m = 0; m < 4; m++) {
        const int ibase = wave_m * 64 + m * 16 + quad * 4;
        #pragma unroll
        for (int reg = 0; reg < 4; reg++) {
            unsigned long long best = ~0ull;
            #pragma unroll
            for (int n = 0; n < 4; n++) {
                const float t = y2v[n] - 2.0f * acc[m][n][reg];
                const unsigned long long key = pack_key(t, (unsigned int)jv[n]);
                best = (key < best) ? key : best;
            }
            atomicMin(&rowmin[ibase + reg], best);
        }
    }
    __syncthreads();
    if (tid < BM) atomicMin(&keys[row0 + tid], rowmin[tid]);
}

// Write both outputs: copy-through everywhere, fused update on [xs, xs+BSZ).
__global__ __launch_bounds__(256)
void finalize_kernel(const float* __restrict__ mind_in, const int* __restrict__ nn_in,
                     const int* __restrict__ xs_p, const int* __restrict__ ys_p,
                     const unsigned long long* __restrict__ keys,
                     const float* __restrict__ x2,
                     float* __restrict__ out_mind, float* __restrict__ out_nn, int N) {
    const int n = blockIdx.x * blockDim.x + threadIdx.x;
    if (n >= N) return;
    const int xs = *xs_p, ys = *ys_p;
    float md  = mind_in[n];
    float nnv = (float)nn_in[n];
    const int i = n - xs;
    if (i >= 0 && i < BSZ) {
        const unsigned long long key = keys[i];
        const float t  = unpack_val(key);
        const float d2 = x2[i] + t;
        const float d  = sqrtf(fmaxf(d2, 0.f));
        md  = fminf(md, d);                                   // min with old buffer
        nnv = (float)((int)(key & 0xFFFFFFFFull) + ys);       // unconditional overwrite
    }
    out_mind[n] = md;
    out_nn[n]  = nnv;
}

extern "C" void kernel_launch(void* const* d_in, const int* in_sizes, int n_in,
                              void* d_out, int out_size, void* d_ws, size_t ws_size,
                              hipStream_t stream) {
    const float* x       = (const float*)d_in[0];
    const float* y       = (const float*)d_in[1];
    const float* mind_in = (const float*)d_in[2];
    const int*   nn_in   = (const int*)d_in[3];
    const int*   xs_p    = (const int*)d_in[4];
    const int*   ys_p    = (const int*)d_in[5];
    const int N = in_sizes[2];            // 50000

    // Workspace layout: [keys u64 x 4096][x2 f32 x 4096][y2 f32 x 4096] = 64 KB
    unsigned long long* keys = (unsigned long long*)d_ws;
    float* x2 = (float*)((char*)d_ws + BSZ * sizeof(unsigned long long));
    float* y2 = x2 + BSZ;

    float* out_mind = (float*)d_out;
    float* out_nn   = out_mind + N;

    norms_init_kernel<<<2 * BSZ, 256, 0, stream>>>(x, y, x2, y2, keys);

    dim3 grid(BSZ / BN, BSZ / BM);        // 32 x 32 = 1024 blocks
    gemm_min_kernel<<<grid, 256, 0, stream>>>(x, y, y2, keys);

    finalize_kernel<<<(N + 255) / 256, 256, 0, stream>>>(
        mind_in, nn_in, xs_p, ys_p, keys, x2, out_mind, out_nn, N);
}

// Round 4
// 463.266 us; speedup vs baseline: 2.8373x; 1.0327x over previous
//
#include <hip/hip_runtime.h>
#include <math.h>

// Problem constants (fixed-shape): B=4096 rows each in x,y; D=3072; N=50000.
#define BSZ 4096
#define DDIM 3072
#define BM 128
#define BN 128
#define BK 32
#define LDK 40   // padded LDS row length in f16 (32 + 8)

typedef _Float16 half8 __attribute__((ext_vector_type(8)));
typedef _Float16 half4 __attribute__((ext_vector_type(4)));
typedef float    floatx4 __attribute__((ext_vector_type(4)));

// Monotonic float->uint mapping so unsigned compare == float compare.
__device__ __forceinline__ unsigned long long pack_key(float t, unsigned int j) {
    unsigned int b = __float_as_uint(t);
    b = (b & 0x80000000u) ? ~b : (b | 0x80000000u);
    return ((unsigned long long)b << 32) | (unsigned long long)j;
}

__device__ __forceinline__ float unpack_val(unsigned long long key) {
    unsigned int ub = (unsigned int)(key >> 32);
    unsigned int b = (ub & 0x80000000u) ? (ub ^ 0x80000000u) : ~ub;
    return __uint_as_float(b);
}

__device__ __forceinline__ void split_f16(float v, _Float16& hi, _Float16& lo) {
    hi = (_Float16)v;
    lo = (_Float16)(v - (float)hi);
}

// =====================================================================
// FAST PATH: pre-split fp32 -> (hi,lo) f16 global arrays + fused norms.
// One block per row (8192 blocks). Also inits keys for x-rows.
// =====================================================================
__global__ __launch_bounds__(256)
void split_norms_kernel(const float* __restrict__ x, const float* __restrict__ y,
                        _Float16* __restrict__ Ahi, _Float16* __restrict__ Alo,
                        _Float16* __restrict__ Bhi, _Float16* __restrict__ Blo,
                        float* __restrict__ x2, float* __restrict__ y2,
                        unsigned long long* __restrict__ keys) {
    const int row = blockIdx.x;              // 0..2*BSZ-1
    const bool isx = row < BSZ;
    const int r = isx ? row : row - BSZ;
    const float* src = (isx ? x : y) + (size_t)r * DDIM;
    _Float16* hid = (isx ? Ahi : Bhi) + (size_t)r * DDIM;
    _Float16* lod = (isx ? Alo : Blo) + (size_t)r * DDIM;

    float s = 0.f;
    #pragma unroll
    for (int c = 0; c < 3; c++) {
        const int pos = (threadIdx.x + 256 * c) * 4;    // 3072 = 256*3*4
        float4 v = *(const float4*)(src + pos);
        s += v.x * v.x + v.y * v.y + v.z * v.z + v.w * v.w;
        half4 hi, lo;
        _Float16 th, tl;
        split_f16(v.x, th, tl); hi.x = th; lo.x = tl;
        split_f16(v.y, th, tl); hi.y = th; lo.y = tl;
        split_f16(v.z, th, tl); hi.z = th; lo.z = tl;
        split_f16(v.w, th, tl); hi.w = th; lo.w = tl;
        *(half4*)(hid + pos) = hi;
        *(half4*)(lod + pos) = lo;
    }
    #pragma unroll
    for (int off = 32; off > 0; off >>= 1) s += __shfl_down(s, off, 64);
    __shared__ float ls[4];
    const int lane = threadIdx.x & 63, w = threadIdx.x >> 6;
    if (lane == 0) ls[w] = s;
    __syncthreads();
    if (threadIdx.x == 0) {
        float tot = ls[0] + ls[1] + ls[2] + ls[3];
        if (isx) { x2[r] = tot; keys[r] = ~0ull; }
        else     { y2[r] = tot; }
    }
}

// =====================================================================
// FAST PATH GEMM: pure f16 K-loop on pre-split data, 3-MFMA emulation
// (hi*hi + hi*lo + lo*hi). Per-row min/argmin via shuffle + atomicMin.
// =====================================================================
__global__ __launch_bounds__(256, 3)
void gemm_min_presplit(const _Float16* __restrict__ Ahi, const _Float16* __restrict__ Alo,
                       const _Float16* __restrict__ Bhi, const _Float16* __restrict__ Blo,
                       const float* __restrict__ y2,
                       unsigned long long* __restrict__ keys) {
    __shared__ _Float16 sAh[BM * LDK];
    __shared__ _Float16 sAl[BM * LDK];
    __shared__ _Float16 sBh[BN * LDK];
    __shared__ _Float16 sBl[BN * LDK];
    __shared__ unsigned long long rowmin[BM];

    const int tid  = threadIdx.x;
    const int row0 = blockIdx.y * BM;
    const int col0 = blockIdx.x * BN;

    const int wid    = tid >> 6;
    const int lane   = tid & 63;
    const int wave_m = wid & 1;
    const int wave_n = wid >> 1;
    const int lrow   = lane & 15;
    const int quad   = lane >> 4;

    floatx4 acc[4][4];
    #pragma unroll
    for (int m = 0; m < 4; m++)
        #pragma unroll
        for (int n = 0; n < 4; n++) acc[m][n] = (floatx4){0.f, 0.f, 0.f, 0.f};

    if (tid < BM) rowmin[tid] = ~0ull;

    // Staging: thread t -> row sr = t>>1, k-half sh = t&1 (16 halves = 32 B).
    const int sr = tid >> 1;
    const int sh = tid & 1;
    const _Float16* pAh = Ahi + (size_t)(row0 + sr) * DDIM + sh * 16;
    const _Float16* pAl = Alo + (size_t)(row0 + sr) * DDIM + sh * 16;
    const _Float16* pBh = Bhi + (size_t)(col0 + sr) * DDIM + sh * 16;
    const _Float16* pBl = Blo + (size_t)(col0 + sr) * DDIM + sh * 16;
    _Float16* wAh = &sAh[sr * LDK + sh * 16];
    _Float16* wAl = &sAl[sr * LDK + sh * 16];
    _Float16* wBh = &sBh[sr * LDK + sh * 16];
    _Float16* wBl = &sBl[sr * LDK + sh * 16];

    for (int k0 = 0; k0 < DDIM; k0 += BK) {
        uint4 vah0 = *(const uint4*)(pAh + k0);
        uint4 vah1 = *(const uint4*)(pAh + k0 + 8);
        uint4 val0 = *(const uint4*)(pAl + k0);
        uint4 val1 = *(const uint4*)(pAl + k0 + 8);
        uint4 vbh0 = *(const uint4*)(pBh + k0);
        uint4 vbh1 = *(const uint4*)(pBh + k0 + 8);
        uint4 vbl0 = *(const uint4*)(pBl + k0);
        uint4 vbl1 = *(const uint4*)(pBl + k0 + 8);
        __syncthreads();   // previous iteration's readers done
        *(uint4*)(wAh + 0) = vah0;  *(uint4*)(wAh + 8) = vah1;
        *(uint4*)(wAl + 0) = val0;  *(uint4*)(wAl + 8) = val1;
        *(uint4*)(wBh + 0) = vbh0;  *(uint4*)(wBh + 8) = vbh1;
        *(uint4*)(wBl + 0) = vbl0;  *(uint4*)(wBl + 8) = vbl1;
        __syncthreads();

        half8 fah[4], fal[4], fbh[4], fbl[4];
        #pragma unroll
        for (int m = 0; m < 4; m++) {
            const int r = wave_m * 64 + m * 16 + lrow;
            fah[m] = *(const half8*)&sAh[r * LDK + quad * 8];
            fal[m] = *(const half8*)&sAl[r * LDK + quad * 8];
        }
        #pragma unroll
        for (int n = 0; n < 4; n++) {
            const int c = wave_n * 64 + n * 16 + lrow;
            fbh[n] = *(const half8*)&sBh[c * LDK + quad * 8];
            fbl[n] = *(const half8*)&sBl[c * LDK + quad * 8];
        }
        // Three passes so adjacent MFMAs never share an accumulator.
        #pragma unroll
        for (int m = 0; m < 4; m++)
            #pragma unroll
            for (int n = 0; n < 4; n++)
                acc[m][n] = __builtin_amdgcn_mfma_f32_16x16x32_f16(fah[m], fbh[n], acc[m][n], 0, 0, 0);
        #pragma unroll
        for (int m = 0; m < 4; m++)
            #pragma unroll
            for (int n = 0; n < 4; n++)
                acc[m][n] = __builtin_amdgcn_mfma_f32_16x16x32_f16(fah[m], fbl[n], acc[m][n], 0, 0, 0);
        #pragma unroll
        for (int m = 0; m < 4; m++)
            #pragma unroll
            for (int n = 0; n < 4; n++)
                acc[m][n] = __builtin_amdgcn_mfma_f32_16x16x32_f16(fal[m], fbh[n], acc[m][n], 0, 0, 0);
    }
    __syncthreads();

    // Epilogue: per-row min/argmin. The 16 lanes of a quad group share rows ->
    // butterfly reduce across them, then 1 atomic per row per wave.
    float y2v[4];
    int   jv[4];
    #pragma unroll
    for (int n = 0; n < 4; n++) {
        jv[n]  = col0 + wave_n * 64 + n * 16 + lrow;
        y2v[n] = y2[jv[n]];
    }
    #pragma unroll
    for (int m = 0; m < 4; m++) {
        #pragma unroll
        for (int reg = 0; reg < 4; reg++) {
            unsigned long long best = ~0ull;
            #pragma unroll
            for (int n = 0; n < 4; n++) {
                const float t = y2v[n] - 2.0f * acc[m][n][reg];
                const unsigned long long key = pack_key(t, (unsigned int)jv[n]);
                best = (key < best) ? key : best;
            }
            #pragma unroll
            for (int s = 1; s < 16; s <<= 1) {
                unsigned long long o = __shfl_xor(best, s, 64);
                best = (o < best) ? o : best;
            }
            if (lrow == 0)
                atomicMin(&rowmin[wave_m * 64 + m * 16 + quad * 4 + reg], best);
        }
    }
    __syncthreads();
    if (tid < BM) atomicMin(&keys[row0 + tid], rowmin[tid]);
}

// =====================================================================
// FALLBACK PATH (small ws): round-2 kernels with in-loop split.
// =====================================================================
__global__ __launch_bounds__(256)
void norms_init_kernel(const float* __restrict__ x, const float* __restrict__ y,
                       float* __restrict__ x2, float* __restrict__ y2,
                       unsigned long long* __restrict__ keys) {
    const int row = blockIdx.x;
    const float* p = (row < BSZ) ? (x + (size_t)row * DDIM)
                                 : (y + (size_t)(row - BSZ) * DDIM);
    const float4* p4 = (const float4*)p;
    float s = 0.f;
    for (int k = threadIdx.x; k < DDIM / 4; k += 256) {
        float4 v = p4[k];
        s += v.x * v.x + v.y * v.y + v.z * v.z + v.w * v.w;
    }
    #pragma unroll
    for (int off = 32; off > 0; off >>= 1) s += __shfl_down(s, off, 64);
    __shared__ float ls[4];
    const int lane = threadIdx.x & 63, w = threadIdx.x >> 6;
    if (lane == 0) ls[w] = s;
    __syncthreads();
    if (threadIdx.x == 0) {
        float tot = ls[0] + ls[1] + ls[2] + ls[3];
        if (row < BSZ) { x2[row] = tot; keys[row] = ~0ull; }
        else           { y2[row - BSZ] = tot; }
    }
}

__global__ __launch_bounds__(256, 3)
void gemm_min_kernel(const float* __restrict__ x, const float* __restrict__ y,
                     const float* __restrict__ y2,
                     unsigned long long* __restrict__ keys) {
    __shared__ _Float16 Ahi[BM * LDK];
    __shared__ _Float16 Alo[BM * LDK];
    __shared__ _Float16 Bhi[BN * LDK];
    __shared__ _Float16 Blo[BN * LDK];
    __shared__ unsigned long long rowmin[BM];

    const int tid  = threadIdx.x;
    const int row0 = blockIdx.y * BM;
    const int col0 = blockIdx.x * BN;
    const int wid    = tid >> 6;
    const int lane   = tid & 63;
    const int wave_m = wid & 1;
    const int wave_n = wid >> 1;
    const int lrow   = lane & 15;
    const int quad   = lane >> 4;

    floatx4 acc[4][4];
    #pragma unroll
    for (int m = 0; m < 4; m++)
        #pragma unroll
        for (int n = 0; n < 4; n++) acc[m][n] = (floatx4){0.f, 0.f, 0.f, 0.f};

    if (tid < BM) rowmin[tid] = ~0ull;

    const int sr = tid >> 1;
    const int sh = tid & 1;
    const float* Asrc = x + (size_t)(row0 + sr) * DDIM + sh * 16;
    const float* Bsrc = y + (size_t)(col0 + sr) * DDIM + sh * 16;
    _Float16* AhiW = &Ahi[sr * LDK + sh * 16];
    _Float16* AloW = &Alo[sr * LDK + sh * 16];
    _Float16* BhiW = &Bhi[sr * LDK + sh * 16];
    _Float16* BloW = &Blo[sr * LDK + sh * 16];

    for (int k0 = 0; k0 < DDIM; k0 += BK) {
        {
            float4 a0 = *(const float4*)(Asrc + k0 + 0);
            float4 a1 = *(const float4*)(Asrc + k0 + 4);
            float4 a2 = *(const float4*)(Asrc + k0 + 8);
            float4 a3 = *(const float4*)(Asrc + k0 + 12);
            float4 b0 = *(const float4*)(Bsrc + k0 + 0);
            float4 b1 = *(const float4*)(Bsrc + k0 + 4);
            float4 b2 = *(const float4*)(Bsrc + k0 + 8);
            float4 b3 = *(const float4*)(Bsrc + k0 + 12);
            float av[16] = {a0.x,a0.y,a0.z,a0.w, a1.x,a1.y,a1.z,a1.w,
                            a2.x,a2.y,a2.z,a2.w, a3.x,a3.y,a3.z,a3.w};
            float bv[16] = {b0.x,b0.y,b0.z,b0.w, b1.x,b1.y,b1.z,b1.w,
                            b2.x,b2.y,b2.z,b2.w, b3.x,b3.y,b3.z,b3.w};
            half8 ah0, ah1, al0, al1, bh0, bh1, bl0, bl1;
            #pragma unroll
            for (int i = 0; i < 8; i++) {
                _Float16 hi, lo;
                split_f16(av[i], hi, lo);     ah0[i] = hi; al0[i] = lo;
                split_f16(av[i + 8], hi, lo); ah1[i] = hi; al1[i] = lo;
                split_f16(bv[i], hi, lo);     bh0[i] = hi; bl0[i] = lo;
                split_f16(bv[i + 8], hi, lo); bh1[i] = hi; bl1[i] = lo;
            }
            __syncthreads();
            *(half8*)(AhiW + 0) = ah0;  *(half8*)(AhiW + 8) = ah1;
            *(half8*)(AloW + 0) = al0;  *(half8*)(AloW + 8) = al1;
            *(half8*)(BhiW + 0) = bh0;  *(half8*)(BhiW + 8) = bh1;
            *(half8*)(BloW + 0) = bl0;  *(half8*)(BloW + 8) = bl1;
        }
        __syncthreads();

        half8 fah[4], fal[4], fbh[4], fbl[4];
        #pragma unroll
        for (int m = 0; m < 4; m++) {
            const int r = wave_m * 64 + m * 16 + lrow;
            fah[m] = *(const half8*)&Ahi[r * LDK + quad * 8];
            fal[m] = *(const half8*)&Alo[r * LDK + quad * 8];
        }
        #pragma unroll
        for (int n = 0; n < 4; n++) {
            const int c = wave_n * 64 + n * 16 + lrow;
            fbh[n] = *(const half8*)&Bhi[c * LDK + quad * 8];
            fbl[n] = *(const half8*)&Blo[c * LDK + quad * 8];
        }
        #pragma unroll
        for (int m = 0; m < 4; m++)
            #pragma unroll
            for (int n = 0; n < 4; n++) {
                acc[m][n] = __builtin_amdgcn_mfma_f32_16x16x32_f16(fah[m], fbh[n], acc[m][n], 0, 0, 0);
                acc[m][n] = __builtin_amdgcn_mfma_f32_16x16x32_f16(fah[m], fbl[n], acc[m][n], 0, 0, 0);
                acc[m][n] = __builtin_amdgcn_mfma_f32_16x16x32_f16(fal[m], fbh[n], acc[m][n], 0, 0, 0);
            }
    }
    __syncthreads();

    float y2v[4];
    int   jv[4];
    #pragma unroll
    for (int n = 0; n < 4; n++) {
        jv[n]  = col0 + wave_n * 64 + n * 16 + lrow;
        y2v[n] = y2[jv[n]];
    }
    #pragma unroll
    for (int m = 0; m < 4; m++) {
        const int ibase = wave_m * 64 + m * 16 + quad * 4;
        #pragma unroll
        for (int reg = 0; reg < 4; reg++) {
            unsigned long long best = ~0ull;
            #pragma unroll
            for (int n = 0; n < 4; n++) {
                const float t = y2v[n] - 2.0f * acc[m][n][reg];
                const unsigned long long key = pack_key(t, (unsigned int)jv[n]);
                best = (key < best) ? key : best;
            }
            atomicMin(&rowmin[ibase + reg], best);
        }
    }
    __syncthreads();
    if (tid < BM) atomicMin(&keys[row0 + tid], rowmin[tid]);
}

// Write both outputs: copy-through everywhere, fused update on [xs, xs+BSZ).
__global__ __launch_bounds__(256)
void finalize_kernel(const float* __restrict__ mind_in, const int* __restrict__ nn_in,
                     const int* __restrict__ xs_p, const int* __restrict__ ys_p,
                     const unsigned long long* __restrict__ keys,
                     const float* __restrict__ x2,
                     float* __restrict__ out_mind, float* __restrict__ out_nn, int N) {
    const int n = blockIdx.x * blockDim.x + threadIdx.x;
    if (n >= N) return;
    const int xs = *xs_p, ys = *ys_p;
    float md  = mind_in[n];
    float nnv = (float)nn_in[n];
    const int i = n - xs;
    if (i >= 0 && i < BSZ) {
        const unsigned long long key = keys[i];
        const float t  = unpack_val(key);
        const float d2 = x2[i] + t;
        const float d  = sqrtf(fmaxf(d2, 0.f));
        md  = fminf(md, d);
        nnv = (float)((int)(key & 0xFFFFFFFFull) + ys);
    }
    out_mind[n] = md;
    out_nn[n]  = nnv;
}

extern "C" void kernel_launch(void* const* d_in, const int* in_sizes, int n_in,
                              void* d_out, int out_size, void* d_ws, size_t ws_size,
                              hipStream_t stream) {
    const float* x       = (const float*)d_in[0];
    const float* y       = (const float*)d_in[1];
    const float* mind_in = (const float*)d_in[2];
    const int*   nn_in   = (const int*)d_in[3];
    const int*   xs_p    = (const int*)d_in[4];
    const int*   ys_p    = (const int*)d_in[5];
    const int N = in_sizes[2];            // 50000

    // ws layout: [keys u64 x4096 | x2 f32 x4096 | y2 f32 x4096 | Ahi | Alo | Bhi | Blo]
    unsigned long long* keys = (unsigned long long*)d_ws;
    float* x2 = (float*)((char*)d_ws + 32768);
    float* y2 = x2 + BSZ;
    const size_t split_bytes = (size_t)BSZ * DDIM * sizeof(_Float16);   // 25165824
    _Float16* Ahi = (_Float16*)((char*)d_ws + 65536);
    _Float16* Alo = (_Float16*)((char*)Ahi + split_bytes);
    _Float16* Bhi = (_Float16*)((char*)Alo + split_bytes);
    _Float16* Blo = (_Float16*)((char*)Bhi + split_bytes);
    const size_t ws_needed = 65536 + 4 * split_bytes;                   // ~96 MB

    float* out_mind = (float*)d_out;
    float* out_nn   = out_mind + N;

    dim3 grid(BSZ / BN, BSZ / BM);        // 32 x 32 = 1024 blocks

    if (ws_size >= ws_needed) {
        split_norms_kernel<<<2 * BSZ, 256, 0, stream>>>(x, y, Ahi, Alo, Bhi, Blo,
                                                        x2, y2, keys);
        gemm_min_presplit<<<grid, 256, 0, stream>>>(Ahi, Alo, Bhi, Blo, y2, keys);
    } else {
        norms_init_kernel<<<2 * BSZ, 256, 0, stream>>>(x, y, x2, y2, keys);
        gemm_min_kernel<<<grid, 256, 0, stream>>>(x, y, y2, keys);
    }

    finalize_kernel<<<(N + 255) / 256, 256, 0, stream>>>(
        mind_in, nn_in, xs_p, ys_p, keys, x2, out_mind, out_nn, N);
}